// Round 1
// baseline (118.050 us; speedup 1.0000x reference)
//
#include <hip/hip_runtime.h>
#include <cstdint>

#define EPS 1e-5f

// x layout: (8, 256, 128, 128) f32, flat plane index p = b*256 + gc in [0,2048)
// Note: reshape (8,256,...)->(256,8,...) preserves contiguity, so p = bg*8 + c.

// ---------------- Pass A: per-plane row sums and col sums ----------------
__global__ __launch_bounds__(256) void passA(const float* __restrict__ x,
                                             float* __restrict__ rowsum,
                                             float* __restrict__ colsum) {
    int p = blockIdx.x;
    int t = threadIdx.x;
    const float4* xp = (const float4*)(x + (size_t)p * 16384);
    float4 csum = {0.f, 0.f, 0.f, 0.f};
    for (int i = 0; i < 16; ++i) {
        float4 v = xp[i * 256 + t];
        csum.x += v.x; csum.y += v.y; csum.z += v.z; csum.w += v.w;
        float rs = v.x + v.y + v.z + v.w;
        // reduce across the 32 threads covering one row (xor masks stay within 32-lane half)
        for (int m = 16; m; m >>= 1) rs += __shfl_xor(rs, m);
        if ((t & 31) == 0) rowsum[p * 128 + i * 8 + (t >> 5)] = rs;
    }
    __shared__ float4 red[256];
    red[t] = csum;
    __syncthreads();
    if (t < 32) {
        float4 s = red[t];
        for (int j = 1; j < 8; ++j) {
            float4 v = red[j * 32 + t];
            s.x += v.x; s.y += v.y; s.z += v.z; s.w += v.w;
        }
        ((float4*)colsum)[p * 32 + t] = s;
    }
}

// ---------------- Pass B: gates sh/sw, analytic x2 means -> x21, global wtilde ----------------
__global__ __launch_bounds__(128) void passB(const float* __restrict__ x,
                                             const float* __restrict__ rowsum,
                                             const float* __restrict__ colsum,
                                             const float* __restrict__ w1,
                                             const float* __restrict__ b1,
                                             const float* __restrict__ w3,
                                             const float* __restrict__ b3,
                                             const float* __restrict__ gn_b,
                                             float* __restrict__ sh,
                                             float* __restrict__ sw,
                                             float* __restrict__ x21,
                                             float* __restrict__ wt) {
    int bg = blockIdx.x;
    int t = threadIdx.x;   // 128 threads
    __shared__ float rs[8][128], cs[8][128];
    __shared__ float S[8], Tm[72], corners[8][4], m2[8];
    __shared__ float w1l[64], b1l[8], x11l[8];

    for (int i = 0; i < 8; ++i) {
        rs[i][t] = rowsum[(bg * 8 + i) * 128 + t];
        cs[i][t] = colsum[(bg * 8 + i) * 128 + t];
    }
    if (t < 64) w1l[t] = w1[t];
    if (t < 8) b1l[t] = b1[t];
    if (t < 8) {
        const float* xp = x + (size_t)(bg * 8 + t) * 16384;
        corners[t][0] = xp[0];                 // (0,0)
        corners[t][1] = xp[127];               // (0,127)
        corners[t][2] = xp[127 * 128];         // (127,0)
        corners[t][3] = xp[127 * 128 + 127];   // (127,127)
    }
    __syncthreads();

    if (t < 8) {
        float s = 0.f;
        for (int y = 0; y < 128; ++y) s += rs[t][y];
        S[t] = s;
    }
    {   // sh/sw for y = t
        const float inv128 = 1.f / 128.f;
        int y = t;
        for (int o = 0; o < 8; ++o) {
            float ar = b1l[o], ac = b1l[o];
            for (int i = 0; i < 8; ++i) {
                ar += w1l[o * 8 + i] * rs[i][y] * inv128;
                ac += w1l[o * 8 + i] * cs[i][y] * inv128;
            }
            sh[(bg * 8 + o) * 128 + y] = 1.f / (1.f + __expf(-ar));
            sw[(bg * 8 + o) * 128 + y] = 1.f / (1.f + __expf(-ac));
        }
    }
    __syncthreads();

    if (t < 72) {   // shifted-window sums T[i][ky][kx] for SAME zero padding
        int i = t / 9, ky = (t % 9) / 3, kx = t % 3;
        float v = S[i];
        if (ky == 0) v -= rs[i][127]; else if (ky == 2) v -= rs[i][0];
        if (kx == 0) v -= cs[i][127]; else if (kx == 2) v -= cs[i][0];
        if (ky == 0 && kx == 0) v += corners[i][3];
        if (ky == 0 && kx == 2) v += corners[i][2];
        if (ky == 2 && kx == 0) v += corners[i][1];
        if (ky == 2 && kx == 2) v += corners[i][0];
        Tm[t] = v;
    }
    __syncthreads();

    if (t < 8) {    // per-output-channel mean of x2
        float acc = 0.f;
        for (int j = 0; j < 72; ++j) acc += w3[t * 72 + j] * Tm[j];
        m2[t] = b3[t] + acc * (1.f / 16384.f);
    }
    __syncthreads();

    if (t == 0) {   // x21 = softmax over channels
        float mx = m2[0];
        for (int i = 1; i < 8; ++i) mx = fmaxf(mx, m2[i]);
        float e[8], s = 0.f;
        for (int i = 0; i < 8; ++i) { e[i] = __expf(m2[i] - mx); s += e[i]; }
        for (int i = 0; i < 8; ++i) x21[bg * 8 + i] = e[i] / s;
    }

    if (bg == 0) {  // global: x11 = softmax(gn_b); collapsed conv weights
        if (t == 0) {
            float mx = gn_b[0];
            for (int i = 1; i < 8; ++i) mx = fmaxf(mx, gn_b[i]);
            float e[8], s = 0.f;
            for (int i = 0; i < 8; ++i) { e[i] = __expf(gn_b[i] - mx); s += e[i]; }
            for (int i = 0; i < 8; ++i) x11l[i] = e[i] / s;
        }
        __syncthreads();
        if (t < 72) {
            float a = 0.f;
            for (int o = 0; o < 8; ++o) a += x11l[o] * w3[o * 72 + t];
            wt[t] = a;
        }
        if (t == 72) {
            float a = 0.f;
            for (int o = 0; o < 8; ++o) a += x11l[o] * b3[o];
            wt[72] = a;  // btilde
        }
    }
}

// ---------------- Pass C: per-plane sum & sumsq of gated ----------------
__global__ __launch_bounds__(256) void passC(const float* __restrict__ x,
                                             const float* __restrict__ sh,
                                             const float* __restrict__ sw,
                                             float* __restrict__ musum,
                                             float* __restrict__ sqsum) {
    int p = blockIdx.x;
    int t = threadIdx.x;
    __shared__ float shl[128];
    __shared__ float4 swl[32];
    if (t < 128) shl[t] = sh[p * 128 + t];
    if (t < 32) swl[t] = ((const float4*)sw)[p * 32 + t];
    __syncthreads();
    const float4* xp = (const float4*)(x + (size_t)p * 16384);
    float4 sw4 = swl[t & 31];
    float s = 0.f, q = 0.f;
    for (int i = 0; i < 16; ++i) {
        float4 v = xp[i * 256 + t];
        float shv = shl[i * 8 + (t >> 5)];
        float g0 = v.x * shv * sw4.x;
        float g1 = v.y * shv * sw4.y;
        float g2 = v.z * shv * sw4.z;
        float g3 = v.w * shv * sw4.w;
        s += g0 + g1 + g2 + g3;
        q += g0 * g0 + g1 * g1 + g2 * g2 + g3 * g3;
    }
    for (int m = 32; m; m >>= 1) { s += __shfl_xor(s, m); q += __shfl_xor(q, m); }
    __shared__ float rsum[4], rsq[4];
    if ((t & 63) == 0) { rsum[t >> 6] = s; rsq[t >> 6] = q; }
    __syncthreads();
    if (t == 0) {
        musum[p] = rsum[0] + rsum[1] + rsum[2] + rsum[3];
        sqsum[p] = rsq[0] + rsq[1] + rsq[2] + rsq[3];
    }
}

// ---------------- Pass D: alpha/beta ----------------
__global__ __launch_bounds__(64) void passD(const float* __restrict__ musum,
                                            const float* __restrict__ sqsum,
                                            const float* __restrict__ x21,
                                            const float* __restrict__ gn_w,
                                            const float* __restrict__ gn_b,
                                            const float* __restrict__ wt,
                                            float* __restrict__ alpha,
                                            float* __restrict__ beta) {
    int bg = blockIdx.x;
    int t = threadIdx.x;
    __shared__ float bs[8];
    if (t < 8) {
        int p = bg * 8 + t;
        float mu = musum[p] * (1.f / 16384.f);
        float ex2 = sqsum[p] * (1.f / 16384.f);
        float var = ex2 - mu * mu;
        float inv = rsqrtf(var + EPS);
        float a = x21[p] * inv * gn_w[t];
        alpha[p] = a;
        bs[t] = x21[p] * (gn_b[t] - mu * inv * gn_w[t]);
    }
    __syncthreads();
    if (t == 0) {
        float s = wt[72];
        for (int i = 0; i < 8; ++i) s += bs[i];
        beta[bg] = s;
    }
}

// ---------------- Pass E: fused collapsed conv + gating + sigmoid + output ----------------
// Tile: one bg x 8 output rows; LDS holds 8ch x 10 rows x 132 cols (halo'd, padded).
__global__ __launch_bounds__(256) void passE(const float* __restrict__ x,
                                             const float* __restrict__ sh,
                                             const float* __restrict__ sw,
                                             const float* __restrict__ alpha,
                                             const float* __restrict__ beta,
                                             const float* __restrict__ wt,
                                             float* __restrict__ out) {
    int blk = blockIdx.x;
    int bg = blk >> 4;
    int r0 = (blk & 15) * 8;
    int t = threadIdx.x;
    __shared__ float tl[8 * 10 * 132];
    __shared__ float swl[8 * 128];
    __shared__ float ashl[64];
    __shared__ float wtl[73];
    __shared__ float betal;
    const size_t pbase = (size_t)(bg * 8) * 16384;

    // load 8ch x 10 rows (r0-1 .. r0+8) with zero padding rows; halo col shift +1
    for (int it = 0; it < 10; ++it) {
        int idx = it * 256 + t;          // 0..2559
        int i = idx / 320, rem = idx % 320;
        int rr = rem / 32, c4 = rem % 32;
        int g = r0 - 1 + rr;
        float4 v = {0.f, 0.f, 0.f, 0.f};
        if (g >= 0 && g < 128)
            v = *(const float4*)(x + pbase + (size_t)i * 16384 + g * 128 + c4 * 4);
        float* d = &tl[(i * 10 + rr) * 132 + 1 + c4 * 4];
        d[0] = v.x; d[1] = v.y; d[2] = v.z; d[3] = v.w;
        if (c4 == 0) d[-1] = 0.f;
        if (c4 == 31) d[4] = 0.f;
    }
    {   // sw for 8 channels
        ((float4*)swl)[t] = ((const float4*)sw)[(size_t)(bg * 8 + (t >> 5)) * 32 + (t & 31)];
    }
    if (t < 64) {
        int i = t >> 3, y = t & 7;
        ashl[t] = alpha[bg * 8 + i] * sh[(bg * 8 + i) * 128 + r0 + y];
    }
    if (t < 73) wtl[t] = wt[t];
    if (t == 255) betal = beta[bg];
    __syncthreads();

    int y = t >> 5;
    int x0 = (t & 31) * 4;
    float acc0, acc1, acc2, acc3;
    acc0 = acc1 = acc2 = acc3 = betal;
    float gv[8][4];
#pragma unroll
    for (int i = 0; i < 8; ++i) {
        const float* base = &tl[(i * 10 + y) * 132 + x0];
#pragma unroll
        for (int ky = 0; ky < 3; ++ky) {
            float4 va = *(const float4*)(base + ky * 132);
            float4 vb = *(const float4*)(base + ky * 132 + 4);
            float w0 = wtl[i * 9 + ky * 3 + 0];
            float w1 = wtl[i * 9 + ky * 3 + 1];
            float w2 = wtl[i * 9 + ky * 3 + 2];
            acc0 += w0 * va.x + w1 * va.y + w2 * va.z;
            acc1 += w0 * va.y + w1 * va.z + w2 * va.w;
            acc2 += w0 * va.z + w1 * va.w + w2 * vb.x;
            acc3 += w0 * va.w + w1 * vb.x + w2 * vb.y;
            if (ky == 1) { gv[i][0] = va.y; gv[i][1] = va.z; gv[i][2] = va.w; gv[i][3] = vb.x; }
        }
        float as = ashl[i * 8 + y];
        float s0 = swl[i * 128 + x0 + 0];
        float s1 = swl[i * 128 + x0 + 1];
        float s2 = swl[i * 128 + x0 + 2];
        float s3 = swl[i * 128 + x0 + 3];
        acc0 += as * s0 * gv[i][0];
        acc1 += as * s1 * gv[i][1];
        acc2 += as * s2 * gv[i][2];
        acc3 += as * s3 * gv[i][3];
    }
    float sg0 = 1.f / (1.f + __expf(-acc0));
    float sg1 = 1.f / (1.f + __expf(-acc1));
    float sg2 = 1.f / (1.f + __expf(-acc2));
    float sg3 = 1.f / (1.f + __expf(-acc3));
    size_t ob = pbase + (size_t)(r0 + y) * 128 + x0;
#pragma unroll
    for (int c = 0; c < 8; ++c) {
        float4 o4 = { gv[c][0] * sg0, gv[c][1] * sg1, gv[c][2] * sg2, gv[c][3] * sg3 };
        *(float4*)(out + ob + (size_t)c * 16384) = o4;
    }
}

extern "C" void kernel_launch(void* const* d_in, const int* in_sizes, int n_in,
                              void* d_out, int out_size, void* d_ws, size_t ws_size,
                              hipStream_t stream) {
    (void)in_sizes; (void)n_in; (void)out_size; (void)ws_size;
    const float* x    = (const float*)d_in[0];
    const float* w1   = (const float*)d_in[1];
    const float* b1   = (const float*)d_in[2];
    const float* w3   = (const float*)d_in[3];
    const float* b3   = (const float*)d_in[4];
    const float* gn_w = (const float*)d_in[5];
    const float* gn_b = (const float*)d_in[6];
    float* out = (float*)d_out;
    float* ws  = (float*)d_ws;

    float* rowsum = ws;                 // 2048*128
    float* colsum = ws + 262144;        // 2048*128
    float* sh     = ws + 524288;        // 2048*128
    float* sw     = ws + 786432;        // 2048*128
    float* x21    = ws + 1048576;       // 2048
    float* musum  = ws + 1050624;       // 2048
    float* sqsum  = ws + 1052672;       // 2048
    float* alpha  = ws + 1054720;       // 2048
    float* beta   = ws + 1056768;       // 256
    float* wt     = ws + 1057024;       // 73 (72 collapsed conv weights + btilde)

    hipLaunchKernelGGL(passA, dim3(2048), dim3(256), 0, stream, x, rowsum, colsum);
    hipLaunchKernelGGL(passB, dim3(256),  dim3(128), 0, stream, x, rowsum, colsum,
                       w1, b1, w3, b3, gn_b, sh, sw, x21, wt);
    hipLaunchKernelGGL(passC, dim3(2048), dim3(256), 0, stream, x, sh, sw, musum, sqsum);
    hipLaunchKernelGGL(passD, dim3(256),  dim3(64),  0, stream, musum, sqsum, x21,
                       gn_w, gn_b, wt, alpha, beta);
    hipLaunchKernelGGL(passE, dim3(4096), dim3(256), 0, stream, x, sh, sw,
                       alpha, beta, wt, out);
}